// Round 8
// baseline (268.295 us; speedup 1.0000x reference)
//
#include <hip/hip_runtime.h>

typedef unsigned short u16;
typedef __attribute__((ext_vector_type(8))) short bf16x8;
typedef __attribute__((ext_vector_type(4))) float f32x4;
typedef __attribute__((ext_vector_type(16))) float f32x16;

__device__ __forceinline__ u16 f2bf(float f) {
    union { float f; unsigned u; } v; v.f = f;
    unsigned r = v.u + 0x7fffu + ((v.u >> 16) & 1u);
    return (u16)(r >> 16);
}

__device__ __forceinline__ void gload16(const void* g, void* l) {
    __builtin_amdgcn_global_load_lds((const __attribute__((address_space(1))) void*)g,
                                     (__attribute__((address_space(3))) void*)l, 16, 0, 0);
}

__device__ __forceinline__ float exp2_fast(float x) {
    float r; asm("v_exp_f32 %0, %1" : "=v"(r) : "v"(x)); return r;
}
__device__ __forceinline__ unsigned cvtpk(float lo, float hi) {
    unsigned r; asm("v_cvt_pk_bf16_f32 %0, %1, %2" : "=v"(r) : "v"(lo), "v"(hi)); return r;
}
__device__ __forceinline__ void permswap(unsigned& a, unsigned& b) {
    asm("v_permlane32_swap_b32 %0, %1" : "+v"(a), "+v"(b));
}
__device__ __forceinline__ f32x16 mfma32(bf16x8 a, bf16x8 b, f32x16 c) {
    return __builtin_amdgcn_mfma_f32_32x32x16_bf16(a, b, c, 0, 0, 0);
}
__device__ __forceinline__ f32x4 mfma16(bf16x8 a, bf16x8 b, f32x4 c) {
    return __builtin_amdgcn_mfma_f32_16x16x32_bf16(a, b, c, 0, 0, 0);
}

// ---------------- fp32 -> bf16 convert (8 elems/thread) ----------------
__global__ void cvt_f32_bf16(const float* __restrict__ in, u16* __restrict__ out, int n) {
    int base = (blockIdx.x * blockDim.x + threadIdx.x) * 8;
    if (base >= n) return;
    float4 a = *reinterpret_cast<const float4*>(in + base);
    float4 b = *reinterpret_cast<const float4*>(in + base + 4);
    u16 o[8] = { f2bf(a.x), f2bf(a.y), f2bf(a.z), f2bf(a.w),
                 f2bf(b.x), f2bf(b.y), f2bf(b.z), f2bf(b.w) };
    *reinterpret_cast<bf16x8*>(out + base) = *reinterpret_cast<const bf16x8*>(o);
}

// ============ 256x256 8-phase GEMM (m201 template, plain HIP) ============
// C[M][N] = A[M][K] * B[N][K]^T, bf16 in, fp32 acc. Requires M=8192, K mult of 128.
// 8 waves (2M x 4N), BK=64. Stage stagger (race-safe): iter j stages
// {B0(j+1), B1(j+1), A0(j+2), A1(j+2)} at phases 1..4 — every DMA overwrite of a
// region is issued >=1 barrier after that region's last ds_read. vmcnt(4) steady.
// 2-bit XOR swizzle col ^= bit2(row)<<4 ^ bit3(row)<<5: 8 accesses/bank (minimum).
template<int OUT_BF16>
__global__ __launch_bounds__(512, 2)
void gemm256(const u16* __restrict__ A, const u16* __restrict__ B,
             void* __restrict__ Cout, int N, int K) {
    __shared__ u16 SA[2][2][8192];   // [dbuf][half(128 rows)][128*64 elems]
    __shared__ u16 SB[2][2][8192];
    const int tid  = threadIdx.x;
    const int lane = tid & 63, w = tid >> 6;
    const int wm = w >> 2, wn = w & 3;            // wave grid 2M x 4N
    const int l15 = lane & 15, lk = (lane >> 4) * 8;

    // XCD-chunked block swizzle
    const int xcd = blockIdx.x & 7, idx = blockIdx.x >> 3;
    const int bm = (xcd * 4 + (idx & 3)) * 256;
    const int bn = (idx >> 2) * 256;

    const int NKT = K >> 6;

    // staging: thread writes phys col (tid&7)*8 at row tid>>3; source col carries
    // the inverse (= same) 2-bit XOR so that read-side swizzle sees logical data.
    const int srow = tid >> 3;
    const int scol = ((tid & 7) * 8) ^ (((tid >> 5) & 1) << 4) ^ (((tid >> 6) & 1) << 5);
    const u16* Asrc = A + (long)(bm + srow) * K + scol;
    const u16* Bsrc = B + (long)(bn + srow) * K + scol;
    const long rowsK = (long)64 * K;

    f32x4 acc[8][4] = {};

    // H = kH*4 + part; part: 0 A-h0, 1 A-h1, 2 B-h0, 3 B-h1
    auto STAGE = [&](int H) {
        if (H >= 4 * NKT) return;
        const int kH = H >> 2, part = H & 3, db = kH & 1, h = part & 1;
        const u16* src; u16* dst;
        if (part < 2) { src = Asrc + (long)(h * 128) * K + kH * 64; dst = &SA[db][h][w * 512]; }
        else          { src = Bsrc + (long)(h * 128) * K + kH * 64; dst = &SB[db][h][w * 512]; }
        gload16(src, dst);
        gload16(src + rowsK, dst + 4096);
    };
    // swizzled LDS read: logical (row, ks, lk) -> physical
    auto LD = [&](const u16* p, int row, int ks) {
        const int col = ((ks << 5) + lk) ^ (((row >> 2) & 1) << 4) ^ (((row >> 3) & 1) << 5);
        return *(const bf16x8*)&p[(row << 6) + col];
    };

    // ---- prologue: issue k0 (4) + k1 A0,A1 (2); require k0 landed ----
    STAGE(0); STAGE(1); STAGE(2); STAGE(3); STAGE(4); STAGE(5);
    asm volatile("s_waitcnt vmcnt(4)" ::: "memory");   // 12 issued, >=8 done = k0
    __builtin_amdgcn_s_barrier();

    for (int j = 0; j < NKT; ++j) {
        const int db = j & 1;
        const u16* pa = &SA[db][wm][0];
        const u16* pb = &SB[db][wn >> 1][0];
        const int brow0 = (wn & 1) * 64;
        bf16x8 af[4][2], ag[4][2], bfr[2][2], bgr[2][2];

        // ---- phase 1: read A m0-3 + B n0-1; stage B-h0(j+1) ----
#pragma unroll
        for (int mi = 0; mi < 4; ++mi) {
            af[mi][0] = LD(pa, mi * 16 + l15, 0);
            af[mi][1] = LD(pa, mi * 16 + l15, 1);
        }
#pragma unroll
        for (int ni = 0; ni < 2; ++ni) {
            bfr[ni][0] = LD(pb, brow0 + ni * 16 + l15, 0);
            bfr[ni][1] = LD(pb, brow0 + ni * 16 + l15, 1);
        }
        STAGE(4 * j + 6);
        __builtin_amdgcn_s_barrier();
        asm volatile("s_waitcnt lgkmcnt(0)" ::: "memory");
        __builtin_amdgcn_s_setprio(1);
#pragma unroll
        for (int ks = 0; ks < 2; ++ks)
#pragma unroll
            for (int mi = 0; mi < 4; ++mi)
#pragma unroll
                for (int ni = 0; ni < 2; ++ni)
                    acc[mi][ni] = mfma16(af[mi][ks], bfr[ni][ks], acc[mi][ni]);
        __builtin_amdgcn_s_setprio(0);
        __builtin_amdgcn_s_barrier();

        // ---- phase 2: read A m4-7; stage B-h1(j+1) ----
#pragma unroll
        for (int mi = 0; mi < 4; ++mi) {
            ag[mi][0] = LD(pa, (4 + mi) * 16 + l15, 0);
            ag[mi][1] = LD(pa, (4 + mi) * 16 + l15, 1);
        }
        STAGE(4 * j + 7);
        __builtin_amdgcn_s_barrier();
        asm volatile("s_waitcnt lgkmcnt(0)" ::: "memory");
        __builtin_amdgcn_s_setprio(1);
#pragma unroll
        for (int ks = 0; ks < 2; ++ks)
#pragma unroll
            for (int mi = 0; mi < 4; ++mi)
#pragma unroll
                for (int ni = 0; ni < 2; ++ni)
                    acc[4 + mi][ni] = mfma16(ag[mi][ks], bfr[ni][ks], acc[4 + mi][ni]);
        __builtin_amdgcn_s_setprio(0);
        __builtin_amdgcn_s_barrier();

        // ---- phase 3: read B n2-3; stage A-h0(j+2) (A last read in ph2 -> safe) ----
#pragma unroll
        for (int ni = 0; ni < 2; ++ni) {
            bgr[ni][0] = LD(pb, brow0 + (2 + ni) * 16 + l15, 0);
            bgr[ni][1] = LD(pb, brow0 + (2 + ni) * 16 + l15, 1);
        }
        STAGE(4 * j + 8);
        __builtin_amdgcn_s_barrier();
        asm volatile("s_waitcnt lgkmcnt(0)" ::: "memory");
        __builtin_amdgcn_s_setprio(1);
#pragma unroll
        for (int ks = 0; ks < 2; ++ks)
#pragma unroll
            for (int mi = 0; mi < 4; ++mi)
#pragma unroll
                for (int ni = 0; ni < 2; ++ni)
                    acc[4 + mi][2 + ni] = mfma16(ag[mi][ks], bgr[ni][ks], acc[4 + mi][2 + ni]);
        __builtin_amdgcn_s_setprio(0);
        __builtin_amdgcn_s_barrier();

        // ---- phase 4: no reads; stage A-h1(j+2); counted vmcnt ----
        STAGE(4 * j + 9);
        if (j < NKT - 2) { asm volatile("s_waitcnt vmcnt(4)" ::: "memory"); }
        else             { asm volatile("s_waitcnt vmcnt(0)" ::: "memory"); }
        __builtin_amdgcn_s_barrier();
        __builtin_amdgcn_s_setprio(1);
#pragma unroll
        for (int ks = 0; ks < 2; ++ks)
#pragma unroll
            for (int mi = 0; mi < 4; ++mi)
#pragma unroll
                for (int ni = 0; ni < 2; ++ni)
                    acc[mi][2 + ni] = mfma16(af[mi][ks], bgr[ni][ks], acc[mi][2 + ni]);
        __builtin_amdgcn_s_setprio(0);
        __builtin_amdgcn_s_barrier();
    }

    // ---- epilogue ----
    const int r0 = (lane >> 4) * 4;
#pragma unroll
    for (int m = 0; m < 8; ++m)
#pragma unroll
        for (int n = 0; n < 4; ++n) {
            long row = bm + wm * 128 + m * 16 + r0;
            long col = bn + wn * 64 + n * 16 + l15;
            if (OUT_BF16) {
                u16* C = (u16*)Cout;
#pragma unroll
                for (int jj = 0; jj < 4; ++jj) C[(row + jj) * N + col] = f2bf(acc[m][n][jj]);
            } else {
                float* C = (float*)Cout;
#pragma unroll
                for (int jj = 0; jj < 4; ++jj) C[(row + jj) * N + col] = acc[m][n][jj];
            }
        }
}

// ---------------- causal flash attention, swapped-operand 32x32 (unchanged) ----------------
template<int RB>
__device__ __forceinline__ bf16x8 pack8(const f32x16& S) {
    unsigned A0 = cvtpk(S[RB + 0], S[RB + 1]);
    unsigned A1 = cvtpk(S[RB + 2], S[RB + 3]);
    unsigned B0 = cvtpk(S[RB + 4], S[RB + 5]);
    unsigned B1 = cvtpk(S[RB + 6], S[RB + 7]);
    permswap(A0, B0);
    permswap(A1, B1);
    union { unsigned u[4]; bf16x8 v; } pk;
    pk.u[0] = A0; pk.u[1] = A1; pk.u[2] = B0; pk.u[3] = B1;
    return pk.v;
}

__global__ __launch_bounds__(256, 4)
void attn_fwd(const u16* __restrict__ qkv, u16* __restrict__ out) {
    const int bh  = blockIdx.x;
    const int b   = bh >> 4, h = bh & 15;
    const int qb  = 15 - (int)blockIdx.y;
    const int tid = threadIdx.x;
    const int lane = tid & 63;
    const int w    = tid >> 6;
    const int l31  = lane & 31;
    const int hi   = lane >> 5;
    const int qw0  = qb * 128 + w * 32;

    __shared__ u16 Ks[2][64 * 64];
    __shared__ u16 Vt[2][64 * 64];

    bf16x8 aq[4];
    {
        const u16* qp = qkv + (long)(b * 2048 + qw0 + l31) * 3072 + h * 64 + hi * 8;
#pragma unroll
        for (int c = 0; c < 4; ++c) aq[c] = *(const bf16x8*)(qp + c * 16);
    }

    f32x16 o0 = {}, o1 = {};
    float m_r = -3e38f, l_r = 0.f;
    const float K2 = 0.18033688011112042f;

    const int krow  = w * 16 + (lane >> 3);
    const int kslot = (lane & 7) ^ (lane >> 3);
    const u16* ksrc0 = qkv + (long)(b * 2048 + krow) * 3072 + 1024 + h * 64 + kslot * 8;
    const u16* vsrc0 = qkv + (long)(b * 2048 + lane) * 3072 + 2048 + h * 64 + w * 16;

    const int nt = 2 * (qb + 1);

    bf16x8 pv0 = *(const bf16x8*)(vsrc0);
    bf16x8 pv1 = *(const bf16x8*)(vsrc0 + 8);
    gload16(ksrc0,                  &Ks[0][w * 1024]);
    gload16(ksrc0 + (long)8 * 3072, &Ks[0][w * 1024 + 512]);

    for (int t = 0; t < nt; ++t) {
        const int cb = t & 1;
#pragma unroll
        for (int i = 0; i < 8; ++i) {
            int d0 = w * 16 + i, d1 = d0 + 8;
            Vt[cb][d0 * 64 + ((((lane >> 3) ^ d0) & 7) << 3) + (lane & 7)] = (u16)pv0[i];
            Vt[cb][d1 * 64 + ((((lane >> 3) ^ d1) & 7) << 3) + (lane & 7)] = (u16)pv1[i];
        }
        __syncthreads();

        if (t + 1 < nt) {
            const long off = (long)(t + 1) * 64 * 3072;
            pv0 = *(const bf16x8*)(vsrc0 + off);
            pv1 = *(const bf16x8*)(vsrc0 + off + 8);
            gload16(ksrc0 + off,                  &Ks[cb ^ 1][w * 1024]);
            gload16(ksrc0 + off + (long)8 * 3072, &Ks[cb ^ 1][w * 1024 + 512]);
        }

        const int kv0 = t * 64;
        if (kv0 <= qw0 + 31) {
            f32x16 s0 = {}, s1 = {};
            __builtin_amdgcn_s_setprio(1);
#pragma unroll
            for (int c = 0; c < 4; ++c) {
                const int sl = 2 * c + hi;
                bf16x8 k0 = *(const bf16x8*)&Ks[cb][l31 * 64        + ((sl ^ (l31 & 7)) << 3)];
                bf16x8 k1 = *(const bf16x8*)&Ks[cb][(l31 + 32) * 64 + ((sl ^ (l31 & 7)) << 3)];
                s0 = mfma32(k0, aq[c], s0);
                s1 = mfma32(k1, aq[c], s1);
            }
            __builtin_amdgcn_s_setprio(0);

            if (kv0 + 63 > qw0) {
                const int qrel = qw0 + l31 - kv0;
#pragma unroll
                for (int r = 0; r < 16; ++r) {
                    const int kl = (r & 3) + 8 * (r >> 2) + 4 * hi;
                    if (kl > qrel)      s0[r] = -3e38f;
                    if (kl + 32 > qrel) s1[r] = -3e38f;
                }
            }

            float mx = -3e38f;
#pragma unroll
            for (int r = 0; r < 16; ++r) mx = fmaxf(mx, fmaxf(s0[r], s1[r]));
            mx = fmaxf(mx, __shfl_xor(mx, 32));
            float mxn = fmaxf(m_r, mx);
            if (!__all(mxn - m_r <= 64.0f)) {
                const float alpha = exp2_fast((m_r - mxn) * K2);
#pragma unroll
                for (int r = 0; r < 16; ++r) { o0[r] *= alpha; o1[r] *= alpha; }
                l_r *= alpha;
                m_r = mxn;
            }
            const float mk = m_r * K2;
            float sum = 0.f;
#pragma unroll
            for (int r = 0; r < 16; ++r) {
                float p0 = exp2_fast(fmaf(s0[r], K2, -mk));
                float p1 = exp2_fast(fmaf(s1[r], K2, -mk));
                s0[r] = p0; s1[r] = p1;
                sum += p0 + p1;
            }
            sum += __shfl_xor(sum, 32);
            l_r += sum;

            bf16x8 pw[4];
            pw[0] = pack8<0>(s0); pw[1] = pack8<8>(s0);
            pw[2] = pack8<0>(s1); pw[3] = pack8<8>(s1);

            __builtin_amdgcn_s_setprio(1);
#pragma unroll
            for (int c = 0; c < 4; ++c) {
                const int sl = 2 * c + hi;
                bf16x8 v0 = *(const bf16x8*)&Vt[cb][l31 * 64        + ((sl ^ (l31 & 7)) << 3)];
                bf16x8 v1 = *(const bf16x8*)&Vt[cb][(l31 + 32) * 64 + ((sl ^ (l31 & 7)) << 3)];
                o0 = mfma32(v0, pw[c], o0);
                o1 = mfma32(v1, pw[c], o1);
            }
            __builtin_amdgcn_s_setprio(0);
        }
    }

    const float rl = 1.0f / l_r;
    u16* op = out + (long)(b * 2048 + qw0 + l31) * 1024 + h * 64;
#pragma unroll
    for (int r = 0; r < 16; ++r) {
        const int d = (r & 3) + 8 * (r >> 2) + 4 * hi;
        op[d]      = f2bf(o0[r] * rl);
        op[d + 32] = f2bf(o1[r] * rl);
    }
}

extern "C" void kernel_launch(void* const* d_in, const int* in_sizes, int n_in,
                              void* d_out, int out_size, void* d_ws, size_t ws_size,
                              hipStream_t stream) {
    const float* x     = (const float*)d_in[0];
    const float* w_qkv = (const float*)d_in[1];
    const float* w_out = (const float*)d_in[2];
    float* out = (float*)d_out;

    char* ws = (char*)d_ws;
    u16* x_bf    = (u16*)(ws);
    u16* wqkv_bf = (u16*)(ws + (16u << 20));
    u16* wout_bf = (u16*)(ws + (22u << 20));
    u16* qkv_bf  = (u16*)(ws + (24u << 20));
    u16* attn_bf = (u16*)(ws + (72u << 20));

    const int nx = 8192 * 1024, nq = 3072 * 1024, no = 1024 * 1024;
    cvt_f32_bf16<<<nx / 8 / 256, 256, 0, stream>>>(x,     x_bf,    nx);
    cvt_f32_bf16<<<nq / 8 / 256, 256, 0, stream>>>(w_qkv, wqkv_bf, nq);
    cvt_f32_bf16<<<no / 8 / 256, 256, 0, stream>>>(w_out, wout_bf, no);

    // qkv = x @ w_qkv^T : M=8192, N=3072, K=1024 -> grid 8*4*(3072/256) = 384
    gemm256<1><<<dim3(384), 512, 0, stream>>>(x_bf, wqkv_bf, qkv_bf, 3072, 1024);

    attn_fwd<<<dim3(64, 16), 256, 0, stream>>>(qkv_bf, attn_bf);

    // out = attn @ w_out^T : M=8192, N=1024, K=1024 -> grid 8*4*(1024/256) = 128
    gemm256<0><<<dim3(128), 512, 0, stream>>>(attn_bf, wout_bf, out, 1024, 1024);
}